// Round 8
// baseline (476.201 us; speedup 1.0000x reference)
//
#include <hip/hip_runtime.h>
#include <hip/hip_bf16.h>
#include <stdint.h>

// NBEATS MoE block — round 8: routed top-2 grouped GEMM (round-4 structure)
// with a DEPTH-3 register-prefetch software pipeline.
// Diagnosis (r4-r7): per-chunk block latency ~2400cy vs ~180cy compute — the
// post-stage vmcnt(0) drain dominates; depth-1 pipelines (r7) re-create it.
// Fix: plain global_load->VGPR prefetch 3 chunks deep. Register deps are
// tracked EXACTLY by the waitcnt pass: the ds_write of chunk c+1 (loaded 3
// iters ago) gets vmcnt(8) — chunks c+2, c+3 stay in flight across the
// barrier. __syncthreads with no pending global stores / LDS-DMA drains
// lgkmcnt only. This is the hipBLASLt "loads in flight across the barrier"
// K-loop, expressed via register dependencies instead of hand asm.
//   gate_cast_k : LN -> logits -> top2 softmax -> gidx/gw; casts x to bf16.
//   assign_k    : per-block LDS ranking + 8 global atomics/block.
//   gemm_k      : 128x128 tile, 4 waves (2x2), 4x4 mfma_f32_16x16x32_bf16,
//                 BK=32, LDS double buffer, one barrier/chunk. Dead-tile
//                 exit via device counts. FINAL fuses gate combine + scatter.

#define B_ROWS 8192
#define I_DIM  512
#define H_DIM  512
#define E_NUM  8
#define T_DIM  608
#define T_PAD  640
#define CAP    2304   // rows per expert segment (capacity)
#define TPE    18     // 128-row tiles per expert = CAP/128
#define NT     144    // total tiles = E_NUM*TPE
#define NPAD   18432  // NT*128

typedef unsigned short ushort_t;
typedef __attribute__((ext_vector_type(8))) __bf16 bf16x8;
typedef __attribute__((ext_vector_type(8))) unsigned short ushort8;
typedef __attribute__((ext_vector_type(4))) float floatx4;

__device__ __forceinline__ ushort_t f2bf(float v) {
  __hip_bfloat16 h = __float2bfloat16(v);
  return __builtin_bit_cast(unsigned short, h);
}

// ---------------------------------------------------------------- gating ----
__global__ __launch_bounds__(256) void gate_cast_k(
    const float* __restrict__ x, const float* __restrict__ gamma,
    const float* __restrict__ beta, const float* __restrict__ Wg,
    ushort_t* __restrict__ xb, int2* __restrict__ gidx, float2* __restrict__ gw)
{
  const int row  = (blockIdx.x * blockDim.x + threadIdx.x) >> 6;
  const int lane = threadIdx.x & 63;
  const float* xr = x + (size_t)row * I_DIM + lane * 8;
  float4 a = *(const float4*)(xr);
  float4 b = *(const float4*)(xr + 4);
  float xs[8] = {a.x, a.y, a.z, a.w, b.x, b.y, b.z, b.w};

  float s = 0.f;
#pragma unroll
  for (int j = 0; j < 8; ++j) s += xs[j];
#pragma unroll
  for (int off = 32; off; off >>= 1) s += __shfl_xor(s, off);
  const float mu = s * (1.0f / I_DIM);

  float vs = 0.f;
#pragma unroll
  for (int j = 0; j < 8; ++j) { float d = xs[j] - mu; vs += d * d; }
#pragma unroll
  for (int off = 32; off; off >>= 1) vs += __shfl_xor(vs, off);
  const float rstd = rsqrtf(vs * (1.0f / I_DIM) + 1e-5f);

  float lg[8] = {0.f, 0.f, 0.f, 0.f, 0.f, 0.f, 0.f, 0.f};
  const float* gmr = gamma + lane * 8;
  const float* btr = beta + lane * 8;
#pragma unroll
  for (int j = 0; j < 8; ++j) {
    const float y = (xs[j] - mu) * rstd * gmr[j] + btr[j];
    const float* wr = Wg + (size_t)(lane * 8 + j) * E_NUM;
#pragma unroll
    for (int e = 0; e < 8; ++e) lg[e] += y * wr[e];
  }
#pragma unroll
  for (int e = 0; e < 8; ++e)
#pragma unroll
    for (int off = 32; off; off >>= 1) lg[e] += __shfl_xor(lg[e], off);

  ushort8 o;
#pragma unroll
  for (int j = 0; j < 8; ++j) o[j] = f2bf(xs[j]);
  *(ushort8*)(xb + (size_t)row * I_DIM + lane * 8) = o;

  if (lane == 0) {
    int i0 = 0; float b0 = lg[0];
#pragma unroll
    for (int e = 1; e < 8; ++e) if (lg[e] > b0) { b0 = lg[e]; i0 = e; }
    int i1 = -1; float b1 = -3.4e38f;
#pragma unroll
    for (int e = 0; e < 8; ++e) if (e != i0 && lg[e] > b1) { b1 = lg[e]; i1 = e; }
    const float w0 = 1.0f / (1.0f + __expf(b1 - b0));
    gidx[row] = make_int2(i0, i1);
    gw[row] = make_float2(w0, 1.0f - w0);
  }
}

// ------------------------------------------------------------ assignment ----
__global__ __launch_bounds__(256) void assign_k(
    const int2* __restrict__ gidx, const float2* __restrict__ gw,
    int* __restrict__ rowmap, float* __restrict__ wmap,
    int* __restrict__ cursor)
{
  __shared__ int lcnt[E_NUM];
  __shared__ int lbase[E_NUM];
  const int tid = threadIdx.x;
  const int row = blockIdx.x * 256 + tid;
  if (tid < E_NUM) lcnt[tid] = 0;
  __syncthreads();
  const int2 g = gidx[row];
  const float2 w = gw[row];
  const int r0 = atomicAdd(&lcnt[g.x], 1);
  const int r1 = atomicAdd(&lcnt[g.y], 1);
  __syncthreads();
  if (tid < E_NUM) lbase[tid] = atomicAdd(&cursor[tid], lcnt[tid]);
  __syncthreads();
  const int p0 = g.x * CAP + lbase[g.x] + r0;
  rowmap[p0] = row; wmap[p0] = w.x;
  const int p1 = g.y * CAP + lbase[g.y] + r1;
  rowmap[p1] = row; wmap[p1] = w.y;
}

// ------------------------------------------------- weight transpose+cast ----
__global__ __launch_bounds__(256) void transpose_cast_k(
    const float* __restrict__ src, ushort_t* __restrict__ dst,
    int R, int C, size_t srcBStr, size_t dstBStr)
{
  __shared__ float tile[32][33];
  src += (size_t)blockIdx.z * srcBStr;
  dst += (size_t)blockIdx.z * dstBStr;
  const int c0 = blockIdx.x * 32, r0 = blockIdx.y * 32;
  const int tx = threadIdx.x, ty = threadIdx.y;
#pragma unroll
  for (int i = 0; i < 4; ++i)
    tile[ty + i * 8][tx] = src[(size_t)(r0 + ty + i * 8) * C + c0 + tx];
  __syncthreads();
#pragma unroll
  for (int i = 0; i < 4; ++i) {
    const int c = c0 + ty + i * 8;
    if (c < C) dst[(size_t)c * R + r0 + tx] = f2bf(tile[tx][ty + i * 8]);
  }
}

// ------------------------------------------------------------------ GEMM ----
// tile t=blockIdx.x -> expert t/TPE, gathered rows [t*128, t*128+128).
template <bool GATHER, bool RELU, bool FINAL>
__global__ __launch_bounds__(256) void gemm_k(
    const ushort_t* __restrict__ A,      // GATHER: xb [8192][K]; else z [NPAD][K]
    const ushort_t* __restrict__ B,      // bf16 [E][N][K]
    size_t bEStr,
    const int* __restrict__ rowmap, const float* __restrict__ wmap,
    const int* __restrict__ cursor,      // live counts per expert
    ushort_t* __restrict__ Z,            // mid out [NPAD][H_DIM]
    float* __restrict__ out)             // final out (split)
{
  constexpr int K = 512;
  constexpr int NCH = K / 32;            // 16 chunks
  __shared__ ushort_t lA[2][128 * 32];
  __shared__ ushort_t lB[2][128 * 32];
  __shared__ float wrow[128];
  __shared__ int rrow[128];

  const int t = blockIdx.x;
  const int e = t / TPE;
  if ((t - e * TPE) * 128 >= cursor[e]) return;  // dead (all-pad) tile
  const int zr0 = t * 128;
  const int bn0 = blockIdx.y * 128;

  const int tid = threadIdx.x, wid = tid >> 6, lane = tid & 63;
  const int sr = wid * 16 + (lane >> 2);   // staging row 0..63
  const int sc = (lane & 3) * 8;           // staging col (elems)

  const ushort_t* Bb = B + (size_t)e * bEStr + (size_t)bn0 * K;
  const ushort_t* gb0 = Bb + (size_t)sr * K + sc;
  const ushort_t* gb1 = gb0 + (size_t)64 * K;
  const ushort_t *ga0, *ga1;
  if (GATHER) {
    ga0 = A + (size_t)rowmap[zr0 + sr] * K + sc;
    ga1 = A + (size_t)rowmap[zr0 + sr + 64] * K + sc;
  } else {
    ga0 = A + (size_t)(zr0 + sr) * K + sc;
    ga1 = ga0 + (size_t)64 * K;
  }

  if (FINAL) {
    if (tid < 128) {
      wrow[tid] = wmap[zr0 + tid];
      rrow[tid] = rowmap[zr0 + tid];
    }
  }

  const int lw = wid * 512 + lane * 8;  // LDS stage offset (elems), 16B/lane

  floatx4 acc[4][4] = {};
  const int wm = (wid >> 1) * 64, wn = (wid & 1) * 64;
  const int fr = lane & 15, q = lane >> 4;

  // depth-3 register prefetch sets (4 x uint4 each)
  uint4 sA0[3], sA1[3], sB0[3], sB1[3];
  auto ld = [&](int c) {
    const int s = c % 3;
    const int k = c * 32;
    sA0[s] = *(const uint4*)(ga0 + k);
    sA1[s] = *(const uint4*)(ga1 + k);
    sB0[s] = *(const uint4*)(gb0 + k);
    sB1[s] = *(const uint4*)(gb1 + k);
  };
  auto stage = [&](int c) {  // ds_write chunk c; waits vmcnt(8) via reg deps
    const int s = c % 3, b = c & 1;
    *(uint4*)(&lA[b][lw])        = sA0[s];
    *(uint4*)(&lA[b][2048 + lw]) = sA1[s];
    *(uint4*)(&lB[b][lw])        = sB0[s];
    *(uint4*)(&lB[b][2048 + lw]) = sB1[s];
  };
  auto compute = [&](int c) {
    const int b = c & 1;
    bf16x8 af[4], bfr[4];
#pragma unroll
    for (int mi = 0; mi < 4; ++mi)
      af[mi] = *(const bf16x8*)(&lA[b][(wm + mi * 16 + fr) * 32 + q * 8]);
#pragma unroll
    for (int ni = 0; ni < 4; ++ni)
      bfr[ni] = *(const bf16x8*)(&lB[b][(wn + ni * 16 + fr) * 32 + q * 8]);
#pragma unroll
    for (int mi = 0; mi < 4; ++mi)
#pragma unroll
      for (int ni = 0; ni < 4; ++ni)
        acc[mi][ni] = __builtin_amdgcn_mfma_f32_16x16x32_bf16(
            af[mi], bfr[ni], acc[mi][ni], 0, 0, 0);
  };

  // prologue: 3 chunks in flight; chunk 0 staged to buf 0.
  ld(0); ld(1); ld(2);
  stage(0);
  __syncthreads();

  // steady state: one barrier per chunk; 2 prefetch sets always in flight.
#pragma unroll
  for (int c = 0; c < NCH; ++c) {
    if (c + 3 < NCH) ld(c + 3);
    compute(c);
    if (c + 1 < NCH) stage(c + 1);   // vmcnt(8): c+2, c+3 stay in flight
    __syncthreads();                 // lgkmcnt only (no global stores/DMA)
  }

  if (!FINAL) {
    // C/D layout: col = lane&15, row = (lane>>4)*4 + reg (m89-verified)
    ushort_t* Zb = Z + (size_t)zr0 * H_DIM + bn0;
#pragma unroll
    for (int mi = 0; mi < 4; ++mi)
#pragma unroll
      for (int r = 0; r < 4; ++r) {
        const int row = wm + mi * 16 + q * 4 + r;
        ushort_t* zr = Zb + (size_t)row * H_DIM + wn + fr;
#pragma unroll
        for (int ni = 0; ni < 4; ++ni) {
          float v = acc[mi][ni][r];
          if (RELU) v = fmaxf(v, 0.0f);
          zr[ni * 16] = f2bf(v);
        }
      }
  } else {
#pragma unroll
    for (int mi = 0; mi < 4; ++mi)
#pragma unroll
      for (int r = 0; r < 4; ++r) {
        const int row = wm + mi * 16 + q * 4 + r;
        const float w = wrow[row];
        if (w != 0.0f) {
          const size_t orig = rrow[row];
#pragma unroll
          for (int ni = 0; ni < 4; ++ni) {
            const int col = bn0 + wn + ni * 16 + fr;
            if (col < T_DIM) {
              const float v = acc[mi][ni][r] * w;
              float* dst = (col < I_DIM)
                  ? out + orig * I_DIM + col
                  : out + (size_t)B_ROWS * I_DIM + orig * (T_DIM - I_DIM) +
                        (col - I_DIM);
              atomicAdd(dst, v);
            }
          }
        }
      }
  }
}

// ---------------------------------------------------------------- launch ----
extern "C" void kernel_launch(void* const* d_in, const int* in_sizes, int n_in,
                              void* d_out, int out_size, void* d_ws,
                              size_t ws_size, hipStream_t stream) {
  const float* x     = (const float*)d_in[0];
  const float* gamma = (const float*)d_in[1];
  const float* beta  = (const float*)d_in[2];
  const float* Wg    = (const float*)d_in[3];
  const float* W0    = (const float*)d_in[4];
  const float* Wmid  = (const float*)d_in[5];
  const float* Wout  = (const float*)d_in[6];
  float* out = (float*)d_out;

  char* ws = (char*)d_ws;
  size_t off = 0;
  auto alloc = [&](size_t bytes) -> char* {
    char* p = ws + off;
    off += (bytes + 255) & ~(size_t)255;
    return p;
  };

  const size_t SQ = (size_t)H_DIM * H_DIM;
  ushort_t* xb    = (ushort_t*)alloc((size_t)B_ROWS * I_DIM * 2);
  ushort_t* W0t   = (ushort_t*)alloc((size_t)E_NUM * SQ * 2);
  ushort_t* Wmidt = (ushort_t*)alloc((size_t)3 * E_NUM * SQ * 2);
  ushort_t* Woutt = (ushort_t*)alloc((size_t)E_NUM * T_PAD * H_DIM * 2);
  int2*   gidx  = (int2*)alloc((size_t)B_ROWS * sizeof(int2));
  float2* gwv   = (float2*)alloc((size_t)B_ROWS * sizeof(float2));
  int*   rmap   = (int*)alloc(NPAD * sizeof(int));
  float* wmap   = (float*)alloc(NPAD * sizeof(float));
  int*   cursor = (int*)alloc(E_NUM * sizeof(int));
  ushort_t* z0 = (ushort_t*)alloc((size_t)NPAD * H_DIM * 2);
  ushort_t* z1 = (ushort_t*)alloc((size_t)NPAD * H_DIM * 2);

  hipMemsetAsync(d_out, 0, (size_t)out_size * sizeof(float), stream);
  hipMemsetAsync(rmap, 0, NPAD * sizeof(int), stream);
  hipMemsetAsync(wmap, 0, NPAD * sizeof(float), stream);
  hipMemsetAsync(cursor, 0, E_NUM * sizeof(int), stream);

  gate_cast_k<<<dim3(B_ROWS / 4), 256, 0, stream>>>(x, gamma, beta, Wg, xb,
                                                    gidx, gwv);
  transpose_cast_k<<<dim3(16, 16, 8), dim3(32, 8), 0, stream>>>(
      W0, W0t, 512, 512, SQ, SQ);
  transpose_cast_k<<<dim3(16, 16, 24), dim3(32, 8), 0, stream>>>(
      Wmid, Wmidt, 512, 512, SQ, SQ);
  transpose_cast_k<<<dim3(19, 16, 8), dim3(32, 8), 0, stream>>>(
      Wout, Woutt, 512, 608, (size_t)512 * 608, (size_t)T_PAD * 512);
  assign_k<<<dim3(B_ROWS / 256), 256, 0, stream>>>(gidx, gwv, rmap, wmap,
                                                   cursor);

  const dim3 gmid(NT, H_DIM / 128);
  const dim3 gfin(NT, T_PAD / 128);
  // z0 = gather(x) @ W0   (no relu)
  gemm_k<true, false, false><<<gmid, 256, 0, stream>>>(
      xb, W0t, SQ, rmap, wmap, cursor, z0, nullptr);
  // z1 = relu(z0 @ Wmid[0])
  gemm_k<false, true, false><<<gmid, 256, 0, stream>>>(
      z0, Wmidt + 0 * E_NUM * SQ, SQ, rmap, wmap, cursor, z1, nullptr);
  // z0 = relu(z1 @ Wmid[1])
  gemm_k<false, true, false><<<gmid, 256, 0, stream>>>(
      z1, Wmidt + 1 * E_NUM * SQ, SQ, rmap, wmap, cursor, z0, nullptr);
  // z1 = relu(z0 @ Wmid[2])
  gemm_k<false, true, false><<<gmid, 256, 0, stream>>>(
      z0, Wmidt + 2 * E_NUM * SQ, SQ, rmap, wmap, cursor, z1, nullptr);
  // out += gate_w * (z1 @ Wout), scattered + split backcast/forecast
  gemm_k<false, false, true><<<gfin, 256, 0, stream>>>(
      z1, Woutt, (size_t)T_PAD * H_DIM, rmap, wmap, cursor, nullptr, out);
}

// Round 9
// 350.212 us; speedup vs baseline: 1.3598x; 1.3598x over previous
//
#include <hip/hip_runtime.h>
#include <hip/hip_bf16.h>
#include <stdint.h>

// NBEATS MoE block — round 9: barrier-free single-wave grouped GEMM.
// r4-r8 evidence: the 4-wave, LDS-staged, barrier-coupled K-loop is
// structurally latency-bound at 2.25 blocks/CU; every software-pipeline
// attempt inside that structure failed (r7 depth-1 vmcnt(0), r8 scratch
// spill of persistent prefetch arrays). Fix: remove the need for barriers.
//   - gemm_k: 64-thread blocks (one wave), wave tile 64x64, acc 4x4 floatx4.
//     A/B fragments loaded DIRECTLY to registers (no LDS, no syncthreads in
//     the K-loop) — pure register deps, exact waitcnt, 9 independent
//     waves/CU hide each other's latency.
//   - Operands pre-swizzled to fragment-contiguous layout [j16][c][lane][8]
//     so every fragment load is one coalesced 1KB global_load_dwordx4:
//     weights by swz_weights_k (replaces transpose), z by the mid epilogue
//     (next layer's A). Only layer-0's gathered x rows stay row-major.
//   gate_cast_k / assign_k: unchanged (r4-validated scheduling).
//   FINAL fuses gate combine + scatter into split out via atomicAdd.

#define B_ROWS 8192
#define I_DIM  512
#define H_DIM  512
#define E_NUM  8
#define T_DIM  608
#define T_PAD  640
#define CAP    2304   // rows per expert segment = 36*64
#define TPE    36     // 64-row tiles per expert
#define NT     288    // total row tiles
#define NPAD   18432  // NT*64

typedef unsigned short ushort_t;
typedef __attribute__((ext_vector_type(8))) __bf16 bf16x8;
typedef __attribute__((ext_vector_type(8))) unsigned short ushort8;
typedef __attribute__((ext_vector_type(4))) float floatx4;

__device__ __forceinline__ ushort_t f2bf(float v) {
  __hip_bfloat16 h = __float2bfloat16(v);
  return __builtin_bit_cast(unsigned short, h);
}

// ---------------------------------------------------------------- gating ----
__global__ __launch_bounds__(256) void gate_cast_k(
    const float* __restrict__ x, const float* __restrict__ gamma,
    const float* __restrict__ beta, const float* __restrict__ Wg,
    ushort_t* __restrict__ xb, int2* __restrict__ gidx, float2* __restrict__ gw)
{
  const int row  = (blockIdx.x * blockDim.x + threadIdx.x) >> 6;
  const int lane = threadIdx.x & 63;
  const float* xr = x + (size_t)row * I_DIM + lane * 8;
  float4 a = *(const float4*)(xr);
  float4 b = *(const float4*)(xr + 4);
  float xs[8] = {a.x, a.y, a.z, a.w, b.x, b.y, b.z, b.w};

  float s = 0.f;
#pragma unroll
  for (int j = 0; j < 8; ++j) s += xs[j];
#pragma unroll
  for (int off = 32; off; off >>= 1) s += __shfl_xor(s, off);
  const float mu = s * (1.0f / I_DIM);

  float vs = 0.f;
#pragma unroll
  for (int j = 0; j < 8; ++j) { float d = xs[j] - mu; vs += d * d; }
#pragma unroll
  for (int off = 32; off; off >>= 1) vs += __shfl_xor(vs, off);
  const float rstd = rsqrtf(vs * (1.0f / I_DIM) + 1e-5f);

  float lg[8] = {0.f, 0.f, 0.f, 0.f, 0.f, 0.f, 0.f, 0.f};
  const float* gmr = gamma + lane * 8;
  const float* btr = beta + lane * 8;
#pragma unroll
  for (int j = 0; j < 8; ++j) {
    const float y = (xs[j] - mu) * rstd * gmr[j] + btr[j];
    const float* wr = Wg + (size_t)(lane * 8 + j) * E_NUM;
#pragma unroll
    for (int e = 0; e < 8; ++e) lg[e] += y * wr[e];
  }
#pragma unroll
  for (int e = 0; e < 8; ++e)
#pragma unroll
    for (int off = 32; off; off >>= 1) lg[e] += __shfl_xor(lg[e], off);

  ushort8 o;
#pragma unroll
  for (int j = 0; j < 8; ++j) o[j] = f2bf(xs[j]);
  *(ushort8*)(xb + (size_t)row * I_DIM + lane * 8) = o;

  if (lane == 0) {
    int i0 = 0; float b0 = lg[0];
#pragma unroll
    for (int e = 1; e < 8; ++e) if (lg[e] > b0) { b0 = lg[e]; i0 = e; }
    int i1 = -1; float b1 = -3.4e38f;
#pragma unroll
    for (int e = 0; e < 8; ++e) if (e != i0 && lg[e] > b1) { b1 = lg[e]; i1 = e; }
    const float w0 = 1.0f / (1.0f + __expf(b1 - b0));
    gidx[row] = make_int2(i0, i1);
    gw[row] = make_float2(w0, 1.0f - w0);
  }
}

// ------------------------------------------------------------ assignment ----
__global__ __launch_bounds__(256) void assign_k(
    const int2* __restrict__ gidx, const float2* __restrict__ gw,
    int* __restrict__ rowmap, float* __restrict__ wmap,
    int* __restrict__ cursor)
{
  __shared__ int lcnt[E_NUM];
  __shared__ int lbase[E_NUM];
  const int tid = threadIdx.x;
  const int row = blockIdx.x * 256 + tid;
  if (tid < E_NUM) lcnt[tid] = 0;
  __syncthreads();
  const int2 g = gidx[row];
  const float2 w = gw[row];
  const int r0 = atomicAdd(&lcnt[g.x], 1);
  const int r1 = atomicAdd(&lcnt[g.y], 1);
  __syncthreads();
  if (tid < E_NUM) lbase[tid] = atomicAdd(&cursor[tid], lcnt[tid]);
  __syncthreads();
  const int p0 = g.x * CAP + lbase[g.x] + r0;
  rowmap[p0] = row; wmap[p0] = w.x;
  const int p1 = g.y * CAP + lbase[g.y] + r1;
  rowmap[p1] = row; wmap[p1] = w.y;
}

// ------------------------------------------------ weight swizzle + cast ----
// src fp32 [z][K=512][N] (K-major, as given) -> dst bf16 fragment-swizzled:
// element (k, n): j=n/16, c=k/32, lane=((k%32)/8)*16 + n%16, u=k%8
// dst idx = ((z*jcount + j)*16 + c)*512 + lane*8 + u.
// Each wave emits one contiguous 1KB fragment block per (j,c).
__global__ __launch_bounds__(256) void swz_weights_k(
    const float* __restrict__ src, ushort_t* __restrict__ dst,
    int N, size_t srcZStr)
{
  const int jcount = gridDim.x;
  const int j = blockIdx.x;
  const int c = blockIdx.y * 4 + (threadIdx.x >> 6);
  const int z = blockIdx.z;
  const int lane = threadIdx.x & 63;
  const int fr = lane & 15, q = lane >> 4;
  const int n = j * 16 + fr;
  const float* s = src + (size_t)z * srcZStr;
  ushort8 o;
#pragma unroll
  for (int u = 0; u < 8; ++u) {
    const int k = c * 32 + q * 8 + u;
    o[u] = (n < N) ? f2bf(s[(size_t)k * N + n]) : (ushort_t)0;
  }
  *(ushort8*)(dst + ((size_t)(z * jcount + j) * 16 + c) * 512 + lane * 8) = o;
}

// ------------------------------------------------------------------ GEMM ----
// One wave per block, 64x64 tile, K=512 (16 chunks), no LDS, no barriers.
// blockIdx.x = n-tile (64 cols), blockIdx.y = row tile t -> expert t/TPE.
template <bool GATHER, bool RELU, bool FINAL>
__global__ __launch_bounds__(64) void gemm_k(
    const ushort_t* __restrict__ A,      // GATHER: xb [8192][512]; else z swz
    const ushort_t* __restrict__ B,      // swizzled [e][NJB][16][64][8]
    int NJB,
    const int* __restrict__ rowmap, const float* __restrict__ wmap,
    const int* __restrict__ cursor,
    ushort_t* __restrict__ Z,            // mid out, swizzled
    float* __restrict__ out)             // final out (split)
{
  const int t = blockIdx.y;
  const int e = t / TPE;
  if ((t - e * TPE) * 64 >= cursor[e]) return;  // dead (all-pad) tile
  const int zr0 = t * 64;
  const int bn0 = blockIdx.x * 64;

  const int lane = threadIdx.x;
  const int fr = lane & 15, q = lane >> 4;

  const ushort_t* Bb =
      B + ((size_t)e * NJB + (bn0 >> 4)) * (16 * 512) + lane * 8;

  const ushort_t *a0, *a1, *a2, *a3;
  if (GATHER) {
    a0 = A + (size_t)rowmap[zr0 + 0 * 16 + fr] * 512 + q * 8;
    a1 = A + (size_t)rowmap[zr0 + 1 * 16 + fr] * 512 + q * 8;
    a2 = A + (size_t)rowmap[zr0 + 2 * 16 + fr] * 512 + q * 8;
    a3 = A + (size_t)rowmap[zr0 + 3 * 16 + fr] * 512 + q * 8;
  } else {
    const ushort_t* Az = A + (size_t)(zr0 >> 4) * (16 * 512) + lane * 8;
    a0 = Az + 0 * 16 * 512;
    a1 = Az + 1 * 16 * 512;
    a2 = Az + 2 * 16 * 512;
    a3 = Az + 3 * 16 * 512;
  }

  floatx4 acc[4][4] = {};

#pragma unroll
  for (int c = 0; c < 16; ++c) {
    const int ao = GATHER ? c * 32 : c * 512;
    bf16x8 af[4], bf[4];
    af[0] = *(const bf16x8*)(a0 + ao);
    af[1] = *(const bf16x8*)(a1 + ao);
    af[2] = *(const bf16x8*)(a2 + ao);
    af[3] = *(const bf16x8*)(a3 + ao);
#pragma unroll
    for (int ni = 0; ni < 4; ++ni)
      bf[ni] = *(const bf16x8*)(Bb + (ni * 16 + c) * 512);
#pragma unroll
    for (int mi = 0; mi < 4; ++mi)
#pragma unroll
      for (int ni = 0; ni < 4; ++ni)
        acc[mi][ni] = __builtin_amdgcn_mfma_f32_16x16x32_bf16(
            af[mi], bf[ni], acc[mi][ni], 0, 0, 0);
  }

  if (!FINAL) {
    // C/D layout: col = lane&15, row = (lane>>4)*4 + reg (m89-verified).
    // Write z in A-fragment-swizzled layout for the next layer.
#pragma unroll
    for (int mi = 0; mi < 4; ++mi) {
      const size_t jbase = (size_t)((zr0 >> 4) + mi) * 16;
#pragma unroll
      for (int ni = 0; ni < 4; ++ni) {
        const int n = bn0 + ni * 16 + fr;       // this layer's out col = next K
        const int cK = n >> 5, qK = (n >> 3) & 3, uK = n & 7;
#pragma unroll
        for (int r = 0; r < 4; ++r) {
          float v = acc[mi][ni][r];
          if (RELU) v = fmaxf(v, 0.0f);
          const int mf = q * 4 + r;             // row within 16-block
          Z[(jbase + cK) * 512 + (qK * 16 + mf) * 8 + uK] = f2bf(v);
        }
      }
    }
  } else {
#pragma unroll
    for (int mi = 0; mi < 4; ++mi)
#pragma unroll
      for (int r = 0; r < 4; ++r) {
        const int row = zr0 + mi * 16 + q * 4 + r;
        const float w = wmap[row];
        if (w != 0.0f) {
          const size_t orig = (size_t)rowmap[row];
#pragma unroll
          for (int ni = 0; ni < 4; ++ni) {
            const int col = bn0 + ni * 16 + fr;
            if (col < T_DIM) {
              const float v = acc[mi][ni][r] * w;
              float* dst = (col < I_DIM)
                  ? out + orig * I_DIM + col
                  : out + (size_t)B_ROWS * I_DIM + orig * (T_DIM - I_DIM) +
                        (col - I_DIM);
              atomicAdd(dst, v);
            }
          }
        }
      }
  }
}

// ---------------------------------------------------------------- launch ----
extern "C" void kernel_launch(void* const* d_in, const int* in_sizes, int n_in,
                              void* d_out, int out_size, void* d_ws,
                              size_t ws_size, hipStream_t stream) {
  const float* x     = (const float*)d_in[0];
  const float* gamma = (const float*)d_in[1];
  const float* beta  = (const float*)d_in[2];
  const float* Wg    = (const float*)d_in[3];
  const float* W0    = (const float*)d_in[4];
  const float* Wmid  = (const float*)d_in[5];
  const float* Wout  = (const float*)d_in[6];
  float* out = (float*)d_out;

  char* ws = (char*)d_ws;
  size_t off = 0;
  auto alloc = [&](size_t bytes) -> char* {
    char* p = ws + off;
    off += (bytes + 255) & ~(size_t)255;
    return p;
  };

  const size_t SQ = (size_t)H_DIM * H_DIM;
  ushort_t* xb    = (ushort_t*)alloc((size_t)B_ROWS * I_DIM * 2);
  ushort_t* W0t   = (ushort_t*)alloc((size_t)E_NUM * SQ * 2);
  ushort_t* Wmidt = (ushort_t*)alloc((size_t)3 * E_NUM * SQ * 2);
  ushort_t* Woutt = (ushort_t*)alloc((size_t)E_NUM * T_PAD * H_DIM * 2);
  int2*   gidx  = (int2*)alloc((size_t)B_ROWS * sizeof(int2));
  float2* gwv   = (float2*)alloc((size_t)B_ROWS * sizeof(float2));
  int*   rmap   = (int*)alloc(NPAD * sizeof(int));
  float* wmap   = (float*)alloc(NPAD * sizeof(float));
  int*   cursor = (int*)alloc(E_NUM * sizeof(int));
  ushort_t* z0 = (ushort_t*)alloc((size_t)NPAD * H_DIM * 2);
  ushort_t* z1 = (ushort_t*)alloc((size_t)NPAD * H_DIM * 2);

  hipMemsetAsync(d_out, 0, (size_t)out_size * sizeof(float), stream);
  hipMemsetAsync(rmap, 0, NPAD * sizeof(int), stream);
  hipMemsetAsync(wmap, 0, NPAD * sizeof(float), stream);
  hipMemsetAsync(cursor, 0, E_NUM * sizeof(int), stream);

  gate_cast_k<<<dim3(B_ROWS / 4), 256, 0, stream>>>(x, gamma, beta, Wg, xb,
                                                    gidx, gwv);
  // weights -> bf16 fragment-swizzled (src is K-major already: [z][K][N])
  swz_weights_k<<<dim3(32, 4, 8), 256, 0, stream>>>(W0, W0t, 512, SQ);
  swz_weights_k<<<dim3(32, 4, 24), 256, 0, stream>>>(Wmid, Wmidt, 512, SQ);
  swz_weights_k<<<dim3(40, 4, 8), 256, 0, stream>>>(Wout, Woutt, 608,
                                                    (size_t)512 * 608);
  assign_k<<<dim3(B_ROWS / 256), 256, 0, stream>>>(gidx, gwv, rmap, wmap,
                                                   cursor);

  const dim3 gmid(H_DIM / 64, NT);   // (8, 288)
  const dim3 gfin(T_PAD / 64, NT);   // (10, 288)
  // z0 = gather(x) @ W0   (no relu)
  gemm_k<true, false, false><<<gmid, 64, 0, stream>>>(
      xb, W0t, 32, rmap, wmap, cursor, z0, nullptr);
  // z1 = relu(z0 @ Wmid[0])
  gemm_k<false, true, false><<<gmid, 64, 0, stream>>>(
      z0, Wmidt + 0 * E_NUM * SQ, 32, rmap, wmap, cursor, z1, nullptr);
  // z0 = relu(z1 @ Wmid[1])
  gemm_k<false, true, false><<<gmid, 64, 0, stream>>>(
      z1, Wmidt + 1 * E_NUM * SQ, 32, rmap, wmap, cursor, z0, nullptr);
  // z1 = relu(z0 @ Wmid[2])
  gemm_k<false, true, false><<<gmid, 64, 0, stream>>>(
      z0, Wmidt + 2 * E_NUM * SQ, 32, rmap, wmap, cursor, z1, nullptr);
  // out += gate_w * (z1 @ Wout), scattered + split backcast/forecast
  gemm_k<false, false, true><<<gfin, 64, 0, stream>>>(
      z1, Woutt, 40, rmap, wmap, cursor, nullptr, out);
}